// Round 1
// baseline (92.125 us; speedup 1.0000x reference)
//
#include <hip/hip_runtime.h>
#include <math.h>

#define MAXN 8400
#define TOPK 10

__global__ __launch_bounds__(256) void taa_kernel(
    const float* __restrict__ scores,   // B,N,C
    const float* __restrict__ boxes,    // B,N,4
    const float* __restrict__ anchors,  // N,2
    const int*   __restrict__ labels,   // B
    const float* __restrict__ gts,      // B,1,4
    float* __restrict__ tb,             // B,N,4
    float* __restrict__ ts,             // B,N,C
    float* __restrict__ fg,             // B,N
    int N, int C)
{
    const int b   = blockIdx.x;
    const int tid = threadIdx.x;

    const float g0 = gts[b*4+0], g1 = gts[b*4+1], g2 = gts[b*4+2], g3 = gts[b*4+3];
    const bool  gt_valid = (g2 > g0) && (g3 > g1);
    const int   cls = labels[b];
    const float gcx = (g0 + g2) * 0.5f, gcy = (g1 + g3) * 0.5f;
    const float area_g = (g2 - g0) * (g3 - g1);

    __shared__ float s_metric[MAXN];
    __shared__ float s_iou[MAXN];
    __shared__ float r_val[256];
    __shared__ int   r_idx[256];
    __shared__ int   s_any;

    if (tid == 0) s_any = 0;
    __syncthreads();

    // Pass 1: per-anchor metric (masked by is_in), iou; track local argmin d2.
    float best_d2 = INFINITY;
    int   best_di = 0x7fffffff;
    int   any_local = 0;

    for (int i = tid; i < N; i += blockDim.x) {
        const float ax = anchors[2*i + 0];
        const float ay = anchors[2*i + 1];
        const bool is_in = (ax >= g0) && (ax <= g2) && (ay >= g1) && (ay <= g3);
        any_local |= (int)is_in;

        const float dx = ax - gcx, dy = ay - gcy;
        const float d2 = dx*dx + dy*dy;
        if (d2 < best_d2) { best_d2 = d2; best_di = i; }  // strided ascending -> first min kept

        const size_t bi4 = ((size_t)b * N + i) * 4;
        const float bx0 = boxes[bi4+0], by0 = boxes[bi4+1];
        const float bx1 = boxes[bi4+2], by1 = boxes[bi4+3];
        const float ix1 = fmaxf(bx0, g0), iy1 = fmaxf(by0, g1);
        const float ix2 = fminf(bx1, g2), iy2 = fminf(by1, g3);
        const float inter = fmaxf(ix2 - ix1, 0.0f) * fmaxf(iy2 - iy1, 0.0f);
        const float area_p = (bx1 - bx0) * (by1 - by0);
        float iou = inter / (area_p + area_g - inter);
        iou = fmaxf(iou, 1e-9f);
        s_iou[i] = iou;

        const float sc = scores[((size_t)b * N + i) * C + cls];
        const float cs = 1.0f / (1.0f + expf(-sc));
        const float i2 = iou * iou;
        const float m  = sqrtf(cs) * (i2 * i2 * i2);

        s_metric[i] = is_in ? m : -1.0f;
    }
    if (any_local) atomicOr(&s_any, 1);
    __syncthreads();

    // Fallback: no anchor inside gt box -> enable only the argmin-d2 anchor.
    if (!s_any) {
        r_val[tid] = best_d2;
        r_idx[tid] = best_di;
        __syncthreads();
        for (int s = 128; s > 0; s >>= 1) {
            if (tid < s) {
                const float v2 = r_val[tid+s]; const int i2x = r_idx[tid+s];
                if (v2 < r_val[tid] || (v2 == r_val[tid] && i2x < r_idx[tid])) {
                    r_val[tid] = v2; r_idx[tid] = i2x;
                }
            }
            __syncthreads();
        }
        if (tid == 0) {
            const int fi = r_idx[0];
            const float sc = scores[((size_t)b * N + fi) * C + cls];
            const float cs = 1.0f / (1.0f + expf(-sc));
            const float iou = s_iou[fi];
            const float i2 = iou * iou;
            s_metric[fi] = sqrtf(cs) * (i2 * i2 * i2);
        }
        __syncthreads();
    }

    // Top-10: sequential block argmax with lowest-index tie-break (top_k stability).
    for (int k = 0; k < TOPK; ++k) {
        float bv = -INFINITY;
        int   bix = 0x7fffffff;
        for (int i = tid; i < N; i += blockDim.x) {
            const float v = s_metric[i];
            if (v > bv) { bv = v; bix = i; }   // ascending stride -> first occurrence kept
        }
        r_val[tid] = bv;
        r_idx[tid] = bix;
        __syncthreads();
        for (int s = 128; s > 0; s >>= 1) {
            if (tid < s) {
                const float v2 = r_val[tid+s]; const int i2x = r_idx[tid+s];
                if (v2 > r_val[tid] || (v2 == r_val[tid] && i2x < r_idx[tid])) {
                    r_val[tid] = v2; r_idx[tid] = i2x;
                }
            }
            __syncthreads();
        }
        const int   wi = r_idx[0];
        const float wv = r_val[0];
        if (tid == 0) {
            s_metric[wi] = -INFINITY;  // remove from further rounds
            const bool sel = (wv >= 0.0f) && gt_valid;
            if (sel) {
                fg[(size_t)b * N + wi] = 1.0f;
                float* tbp = tb + ((size_t)b * N + wi) * 4;
                tbp[0] = g0; tbp[1] = g1; tbp[2] = g2; tbp[3] = g3;
                ts[((size_t)b * N + wi) * C + cls] = s_iou[wi];
            }
        }
        __syncthreads();
    }
}

extern "C" void kernel_launch(void* const* d_in, const int* in_sizes, int n_in,
                              void* d_out, int out_size, void* d_ws, size_t ws_size,
                              hipStream_t stream) {
    const float* scores  = (const float*)d_in[0];
    const float* boxes   = (const float*)d_in[1];
    const float* anchors = (const float*)d_in[2];
    const int*   labels  = (const int*)d_in[3];
    const float* gts     = (const float*)d_in[4];

    const int B = in_sizes[3];
    const int N = in_sizes[2] / 2;
    const int C = in_sizes[0] / (B * N);

    float* tb = (float*)d_out;
    float* ts = tb + (size_t)B * N * 4;
    float* fg = ts + (size_t)B * N * C;

    // Outputs are almost entirely zeros; zero-fill then scatter the few winners.
    hipMemsetAsync(d_out, 0, (size_t)out_size * sizeof(float), stream);

    taa_kernel<<<B, 256, 0, stream>>>(scores, boxes, anchors, labels, gts,
                                      tb, ts, fg, N, C);
}